// Round 13
// baseline (41.671 us; speedup 1.0000x reference)
//
#include <hip/hip_runtime.h>

// Problem constants (b=4, n=64, d=64, E=4096)
// zt layout: [b][d][i][k] -> ((b*64+d)*64+i)*64+k   (4 MB)
// a1[r][e], a3[r][e] : r = b*64+i (node row), 64 KB each
//
// R13: TWO dispatches.
//  K1 = R9-verbatim (pathlin + node MLP + nodeproj), proven.
//  K2 = fused tropical+upath per (b,i) row: stage R[d][k]=zt[b][:][i][:]
//       (16KB contiguous), tropical via coalesced global column stream
//       (A_d[k][lane]) + LDS b32 broadcasts, z2 written back into LDS
//       in-place (wave-private rows), barrier, then the proven u_path GEMM.
//       Removes: 1 launch, 4MB zt2 write + 4MB read, one stage+sync chain.

// K1: z = pe@Whz + bhz (transposed store) + node MLP + nodeproj. grid = 256 (bi)
__global__ __launch_bounds__(1024) void k_pathlin_node(
    const float* __restrict__ ne, const float* __restrict__ pe,
    const int* __restrict__ eidx,
    const float* __restrict__ Whz, const float* __restrict__ bhz,
    const float* __restrict__ Wzz,
    const float* __restrict__ Wnm, const float* __restrict__ bnm,
    float* __restrict__ zt, float* __restrict__ a1, float* __restrict__ a3,
    float* __restrict__ out0) {
  int bi = blockIdx.x;                    // b*64 + i == node row
  int b = bi >> 6, i = bi & 63;
  int t = threadIdx.x, lane = t & 63, w = t >> 6;   // 16 waves
  __shared__ float sP[4096];              // pe tile [k][c], 16KB
  __shared__ float sW[4096];              // Whz [c][d], 16KB
  __shared__ float part[16][64];
  __shared__ float nl[64], al[64];
  ((float4*)sP)[t] = ((const float4*)(pe + (size_t)bi * 4096))[t];
  ((float4*)sW)[t] = ((const float4*)Whz)[t];
  float bv = bhz[lane];
  if (w == 0) nl[lane] = ne[bi * 64 + lane];
  __syncthreads();
  // compute: lane = d, wave w owns k in [w*4, w*4+4)
  float acc[4] = {bv, bv, bv, bv};
  int k0 = w * 4;
#pragma unroll
  for (int c = 0; c < 64; c += 4) {
    float w0 = sW[(c + 0) * 64 + lane], w1 = sW[(c + 1) * 64 + lane];
    float w2 = sW[(c + 2) * 64 + lane], w3 = sW[(c + 3) * 64 + lane];
#pragma unroll
    for (int kk = 0; kk < 4; ++kk) {
      const float4 p = *(const float4*)&sP[(k0 + kk) * 64 + c];  // broadcast b128
      acc[kk] += p.x * w0 + p.y * w1 + p.z * w2 + p.w * w3;
    }
  }
  // transposed store: d = lane, 4 consecutive k -> one float4
  float* dst = zt + (size_t)b * 262144 + (size_t)lane * 4096 + (size_t)i * 64 + k0;
  *(float4*)dst = make_float4(acc[0], acc[1], acc[2], acc[3]);
  __syncthreads();                        // pe tile dead; alias as elist
  // ---- node MLP row bi: wave w scans edges [w*256, (w+1)*256) ----
  int* elist = (int*)sP;                  // 4096 ints = 16KB
  const int* srcv = eidx;
  const int* dstv = eidx + 4096;
  int cntw = 0;
  unsigned long long ltmask = (lane == 63) ? 0x7fffffffffffffffull
                                           : ((1ull << lane) - 1ull);
#pragma unroll
  for (int q = 0; q < 4; ++q) {
    int e2 = w * 256 + q * 64 + lane;
    bool match = (dstv[e2] == bi);
    unsigned long long mask = __ballot(match);
    if (match) {
      int pos = cntw + __popcll(mask & ltmask);
      elist[w * 256 + pos] = srcv[e2];
    }
    cntw += __popcll(mask);
  }
  float accA = 0.f;
  for (int m = 0; m < cntw; ++m) accA += ne[elist[w * 256 + m] * 64 + lane];
  part[w][lane] = accA;
  __syncthreads();
  if (w == 0) {
    float s = 0.f;
#pragma unroll
    for (int p2 = 0; p2 < 16; ++p2) s += part[p2][lane];
    al[lane] = s;
  } else if (w == 2) {                    // nodeproj a1
    const float* nr = ne + bi * 64;
    float s1 = 0.f;
    for (int d2 = 0; d2 < 64; ++d2) s1 += nr[d2] * Wzz[d2 * 64 + lane];
    a1[bi * 64 + lane] = s1;
  } else if (w == 3) {                    // nodeproj a3
    const float* nr = ne + bi * 64;
    float s3 = 0.f;
    for (int d2 = 0; d2 < 64; ++d2) s3 += nr[d2] * Wzz[(128 + d2) * 64 + lane];
    a3[bi * 64 + lane] = s3;
  }
  __syncthreads();
  // u_node partials: wave w handles d2 in [w*4, w*4+4)
  {
    float s = 0.f;
#pragma unroll
    for (int dd = 0; dd < 4; ++dd) {
      int d2 = w * 4 + dd;
      s += nl[d2] * Wnm[d2 * 64 + lane] + al[d2] * Wnm[(64 + d2) * 64 + lane];
    }
    part[w][lane] = s;
  }
  __syncthreads();
  if (w == 0) {
    float v = bnm[lane];
#pragma unroll
    for (int p2 = 0; p2 < 16; ++p2) v += part[p2][lane];
    v = fmaxf(v, 0.f);
    out0[bi * 64 + lane] = v + nl[lane];
  }
}

// K2: fused tropical + u_path per (b,i) row. grid = 256 (bi)
__global__ __launch_bounds__(1024) void k_tropupath(
    const float* __restrict__ zt, const float* __restrict__ Wzz,
    const float* __restrict__ bzz, const float* __restrict__ a1,
    const float* __restrict__ a3, const float* __restrict__ pe,
    float* __restrict__ out1) {
  int bi = blockIdx.x;                    // b*64 + i
  int b = bi >> 6, i = bi & 63;
  int t = threadIdx.x, lane = t & 63, w = t >> 6;   // 16 waves
  __shared__ float R[4096];               // R[d][k] = zt[b][d][i][k]; later z2[d][j]
  // stage R: thread t loads 4 floats of row d = t>>4 (256B contiguous per d)
  {
    int d = t >> 4, ko = (t & 15) * 4;
    *(float4*)&R[d * 64 + ko] = *(const float4*)(
        zt + (size_t)b * 262144 + (size_t)d * 4096 + (size_t)i * 64 + ko);
  }
  // overlap with stage: W2 column regs + GEMM base (global, L2-hot)
  float wreg[64];
#pragma unroll
  for (int d = 0; d < 64; ++d) wreg[d] = Wzz[(64 + d) * 64 + lane];
  float base = a1[bi * 64 + lane] + bzz[lane];
  __syncthreads();
  // ---- tropical: wave w owns d-rows [w*4, w*4+4); lane = j ----
  // z2[d][j] = max(R[d][j], max_k R[d][k] + A_d[k][j]),  A_d = zt[b][d]
  {
    int d0 = w * 4;
    const float* A0 = zt + (size_t)b * 262144 + (size_t)(d0 + 0) * 4096;
    const float* A1 = A0 + 4096;
    const float* A2 = A1 + 4096;
    const float* A3 = A2 + 4096;
    float acc0 = R[(d0 + 0) * 64 + lane];
    float acc1 = R[(d0 + 1) * 64 + lane];
    float acc2 = R[(d0 + 2) * 64 + lane];
    float acc3 = R[(d0 + 3) * 64 + lane];
#pragma unroll 8
    for (int k = 0; k < 64; ++k) {
      float r0 = R[(d0 + 0) * 64 + k];    // LDS b32 broadcast (wave-uniform)
      float r1 = R[(d0 + 1) * 64 + k];
      float r2 = R[(d0 + 2) * 64 + k];
      float r3 = R[(d0 + 3) * 64 + k];
      float a0 = A0[k * 64 + lane];       // global, coalesced 256B/wave
      float a1v = A1[k * 64 + lane];
      float a2v = A2[k * 64 + lane];
      float a3v = A3[k * 64 + lane];
      acc0 = fmaxf(acc0, r0 + a0);
      acc1 = fmaxf(acc1, r1 + a1v);
      acc2 = fmaxf(acc2, r2 + a2v);
      acc3 = fmaxf(acc3, r3 + a3v);
    }
    // write z2 rows in place (wave-private rows; reads of R[d0..d0+3] done)
    R[(d0 + 0) * 64 + lane] = acc0;
    R[(d0 + 1) * 64 + lane] = acc1;
    R[(d0 + 2) * 64 + lane] = acc2;
    R[(d0 + 3) * 64 + lane] = acc3;
  }
  __syncthreads();
  // ---- u_path GEMM (proven K3 body): lane = e, wave w owns j in [w*4,w*4+4) ----
  int j0 = w * 4;
  float acc[4] = {base, base, base, base};
#pragma unroll
  for (int d = 0; d < 64; ++d) {
    const float4 z4 = *(const float4*)&R[d * 64 + j0];    // broadcast b128
    float wv = wreg[d];
    acc[0] += z4.x * wv;
    acc[1] += z4.y * wv;
    acc[2] += z4.z * wv;
    acc[3] += z4.w * wv;
  }
  const float* a3b = a3 + (size_t)b * 4096;
  size_t ob = (size_t)bi * 4096 + (size_t)j0 * 64;
#pragma unroll
  for (int jj = 0; jj < 4; ++jj) {
    float v = acc[jj] + a3b[(j0 + jj) * 64 + lane];
    v = fmaxf(v, 0.f);
    out1[ob + jj * 64 + lane] = v + pe[ob + jj * 64 + lane];
  }
}

extern "C" void kernel_launch(void* const* d_in, const int* in_sizes, int n_in,
                              void* d_out, int out_size, void* d_ws, size_t ws_size,
                              hipStream_t stream) {
  const float* node = (const float*)d_in[0];
  const float* pe   = (const float*)d_in[1];
  const int*   eidx = (const int*)d_in[2];
  const float* Whz  = (const float*)d_in[3];
  const float* bhz  = (const float*)d_in[4];
  const float* Wzz  = (const float*)d_in[5];
  const float* bzz  = (const float*)d_in[6];
  const float* Wnm  = (const float*)d_in[7];
  const float* bnm  = (const float*)d_in[8];
  float* out0 = (float*)d_out;
  float* out1 = out0 + 16384;
  float* zt  = (float*)d_ws;                // 4 MB
  float* a1  = zt + 1048576;                // 64 KB
  float* a3  = a1 + 16384;                  // 64 KB

  hipLaunchKernelGGL(k_pathlin_node, dim3(256), dim3(1024), 0, stream,
                     node, pe, eidx, Whz, bhz, Wzz, Wnm, bnm, zt, a1, a3, out0);
  hipLaunchKernelGGL(k_tropupath, dim3(256), dim3(1024), 0, stream,
                     zt, Wzz, bzz, a1, a3, pe, out1);
}

// Round 14
// 27.642 us; speedup vs baseline: 1.5076x; 1.5076x over previous
//
#include <hip/hip_runtime.h>

// Problem constants (b=4, n=64, d=64, E=4096)
// zt  layout: [b][d][i][k] -> ((b*64+d)*64+i)*64+k   (4 MB)
// zt2: tropical output, same layout (4 MB)
// a1[r][e], a3[r][e] : r = b*64+i (node row), 64 KB each
//
// R14 = R9 pipeline with every block halved: 512 blocks x 512 threads
// (2 blocks/CU, 16 waves/CU total) -> two independent stage->compute chains
// per CU overlap latency. Node MLP + nodeproj ride as K2 tail blocks.

// K1: z = pe@Whz + bhz, transposed store. grid = 512: (bi, k-half)
__global__ __launch_bounds__(512) void k_pathlin(
    const float* __restrict__ pe, const float* __restrict__ Whz,
    const float* __restrict__ bhz, float* __restrict__ zt) {
  int blk = blockIdx.x;
  int bi = blk >> 1, kh = blk & 1;
  int b = bi >> 6, i = bi & 63;
  int t = threadIdx.x, lane = t & 63, w = t >> 6;   // 8 waves
  __shared__ float sP[2048];              // pe rows [kh*32, +32): [32][64] 8KB
  __shared__ float sW[4096];              // Whz [c][d] 16KB
  ((float4*)sP)[t] = ((const float4*)(pe + (size_t)bi * 4096 + kh * 2048))[t];
  ((float4*)sW)[t]       = ((const float4*)Whz)[t];
  ((float4*)sW)[t + 512] = ((const float4*)Whz)[t + 512];
  float bv = bhz[lane];
  __syncthreads();
  // lane = d, wave w owns local rows [w*4, w*4+4)
  float acc[4] = {bv, bv, bv, bv};
  int kl = w * 4;
#pragma unroll
  for (int c = 0; c < 64; c += 4) {
    float w0 = sW[(c + 0) * 64 + lane], w1 = sW[(c + 1) * 64 + lane];
    float w2 = sW[(c + 2) * 64 + lane], w3 = sW[(c + 3) * 64 + lane];
#pragma unroll
    for (int kk = 0; kk < 4; ++kk) {
      const float4 p = *(const float4*)&sP[(kl + kk) * 64 + c];  // broadcast b128
      acc[kk] += p.x * w0 + p.y * w1 + p.z * w2 + p.w * w3;
    }
  }
  int k0 = kh * 32 + kl;
  float* dst = zt + (size_t)b * 262144 + (size_t)lane * 4096 + (size_t)i * 64 + k0;
  *(float4*)dst = make_float4(acc[0], acc[1], acc[2], acc[3]);
}

// K2: blocks [0,512): tropical i-half per (b,d) slice; [512,768): node+nodeproj
__global__ __launch_bounds__(512) void k_trop_node(
    const float* __restrict__ zt, float* __restrict__ zt2,
    const float* __restrict__ ne, const int* __restrict__ eidx,
    const float* __restrict__ Wzz, const float* __restrict__ Wnm,
    const float* __restrict__ bnm,
    float* __restrict__ a1, float* __restrict__ a3, float* __restrict__ out0) {
  int t = threadIdx.x, lane = t & 63, w = t >> 6;   // 8 waves
  __shared__ int elist[4096];             // 16KB; first 8KB aliased as A
  __shared__ float part[8][64];
  __shared__ float nlal[2][64];
  float* A = (float*)elist;
  if (blockIdx.x < 512) {
    int slice = blockIdx.x >> 1, ih = blockIdx.x & 1;   // slice = b*64+d
    const float* Ag = zt + (size_t)slice * 4096;
    // stage rows [ih*32, ih*32+32) (8KB, coalesced)
    ((float4*)A)[t] = ((const float4*)(Ag + ih * 2048))[t];
    // per-lane column from global (coalesced, L2-hot; R12-proven)
    float colreg[64];
#pragma unroll
    for (int k = 0; k < 64; ++k) colreg[k] = Ag[k * 64 + lane];
    int il = w * 4, i0 = ih * 32 + il;
    float acc[4];
#pragma unroll
    for (int ii = 0; ii < 4; ++ii) acc[ii] = Ag[(i0 + ii) * 64 + lane];  // max(zc,z)
    __syncthreads();
#pragma unroll
    for (int k = 0; k < 64; k += 4) {
#pragma unroll
      for (int ii = 0; ii < 4; ++ii) {
        const float4 a = *(const float4*)&A[(il + ii) * 64 + k];  // broadcast b128
        float m0 = fmaxf(a.x + colreg[k], a.y + colreg[k + 1]);
        float m1 = fmaxf(a.z + colreg[k + 2], a.w + colreg[k + 3]);
        acc[ii] = fmaxf(acc[ii], fmaxf(m0, m1));
      }
    }
    float* Og = zt2 + (size_t)slice * 4096 + (size_t)i0 * 64;
#pragma unroll
    for (int ii = 0; ii < 4; ++ii) Og[ii * 64 + lane] = acc[ii];
  } else {
    int r = blockIdx.x - 512;             // node row
    const int* srcv = eidx;
    const int* dstv = eidx + 4096;
    // wave w scans edges [w*512, (w+1)*512) with ballot compaction
    int cntw = 0;
    unsigned long long ltmask = (lane == 63) ? 0x7fffffffffffffffull
                                             : ((1ull << lane) - 1ull);
#pragma unroll
    for (int q = 0; q < 8; ++q) {
      int e2 = w * 512 + q * 64 + lane;
      bool match = (dstv[e2] == r);
      unsigned long long mask = __ballot(match);
      if (match) {
        int pos = cntw + __popcll(mask & ltmask);
        elist[w * 512 + pos] = srcv[e2];
      }
      cntw += __popcll(mask);
    }
    float accA = 0.f;
    for (int m = 0; m < cntw; ++m) accA += ne[elist[w * 512 + m] * 64 + lane];
    part[w][lane] = accA;
    if (w == 0) nlal[0][lane] = ne[r * 64 + lane];
    __syncthreads();
    if (w == 0) {
      float s = 0.f;
#pragma unroll
      for (int p2 = 0; p2 < 8; ++p2) s += part[p2][lane];
      nlal[1][lane] = s;
    } else if (w == 2) {                  // nodeproj a1
      const float* nr = ne + r * 64;
      float s1 = 0.f;
      for (int d2 = 0; d2 < 64; ++d2) s1 += nr[d2] * Wzz[d2 * 64 + lane];
      a1[r * 64 + lane] = s1;
    } else if (w == 3) {                  // nodeproj a3
      const float* nr = ne + r * 64;
      float s3 = 0.f;
      for (int d2 = 0; d2 < 64; ++d2) s3 += nr[d2] * Wzz[(128 + d2) * 64 + lane];
      a3[r * 64 + lane] = s3;
    }
    __syncthreads();
    // u_node partials: wave w handles d2 in [w*8, w*8+8)
    {
      float s = 0.f;
#pragma unroll
      for (int dd = 0; dd < 8; ++dd) {
        int d2 = w * 8 + dd;
        s += nlal[0][d2] * Wnm[d2 * 64 + lane]
           + nlal[1][d2] * Wnm[(64 + d2) * 64 + lane];
      }
      part[w][lane] = s;
    }
    __syncthreads();
    if (w == 0) {
      float v = bnm[lane];
#pragma unroll
      for (int p2 = 0; p2 < 8; ++p2) v += part[p2][lane];
      v = fmaxf(v, 0.f);
      out0[r * 64 + lane] = v + nlal[0][lane];
    }
  }
}

// K3: u_path = relu(a1 + z2@W2 + a3 + bzz) + pe. grid = 512: (bi, j-half)
__global__ __launch_bounds__(512) void k_upath(
    const float* __restrict__ zt2, const float* __restrict__ Wzz,
    const float* __restrict__ bzz, const float* __restrict__ a1,
    const float* __restrict__ a3, const float* __restrict__ pe,
    float* __restrict__ out1) {
  int blk = blockIdx.x;
  int bi = blk >> 1, jh = blk & 1;
  int b = bi >> 6, i = bi & 63;
  int t = threadIdx.x, lane = t & 63, w = t >> 6;   // 8 waves
  __shared__ float sZ[2048];              // [64 d][32 j] 8KB
  {
    int d2 = t >> 3, jo = (t & 7) * 4;    // gather z2[b][d][i][jh*32+jo ..+3]
    const float* src = zt2 + (size_t)b * 262144 + (size_t)d2 * 4096
                     + (size_t)i * 64 + jh * 32 + jo;
    *(float4*)&sZ[d2 * 32 + jo] = *(const float4*)src;
  }
  // per-lane W2 column from global (coalesced, L2-hot; R12-proven)
  float wreg[64];
#pragma unroll
  for (int d = 0; d < 64; ++d) wreg[d] = Wzz[(64 + d) * 64 + lane];
  float base = a1[bi * 64 + lane] + bzz[lane];
  __syncthreads();
  int jl = w * 4, j0 = jh * 32 + jl;
  float acc[4] = {base, base, base, base};
#pragma unroll
  for (int d = 0; d < 64; ++d) {
    const float4 z4 = *(const float4*)&sZ[d * 32 + jl];   // broadcast b128
    float wv = wreg[d];
    acc[0] += z4.x * wv;
    acc[1] += z4.y * wv;
    acc[2] += z4.z * wv;
    acc[3] += z4.w * wv;
  }
  const float* a3b = a3 + (size_t)b * 4096;
  size_t ob = (size_t)bi * 4096 + (size_t)j0 * 64;
#pragma unroll
  for (int jj = 0; jj < 4; ++jj) {
    float v = acc[jj] + a3b[(j0 + jj) * 64 + lane];
    v = fmaxf(v, 0.f);
    out1[ob + jj * 64 + lane] = v + pe[ob + jj * 64 + lane];
  }
}

extern "C" void kernel_launch(void* const* d_in, const int* in_sizes, int n_in,
                              void* d_out, int out_size, void* d_ws, size_t ws_size,
                              hipStream_t stream) {
  const float* node = (const float*)d_in[0];
  const float* pe   = (const float*)d_in[1];
  const int*   eidx = (const int*)d_in[2];
  const float* Whz  = (const float*)d_in[3];
  const float* bhz  = (const float*)d_in[4];
  const float* Wzz  = (const float*)d_in[5];
  const float* bzz  = (const float*)d_in[6];
  const float* Wnm  = (const float*)d_in[7];
  const float* bnm  = (const float*)d_in[8];
  float* out0 = (float*)d_out;
  float* out1 = out0 + 16384;
  float* zt  = (float*)d_ws;                // 4 MB
  float* zt2 = zt + 1048576;                // 4 MB
  float* a1  = zt2 + 1048576;               // 64 KB
  float* a3  = a1 + 16384;                  // 64 KB

  hipLaunchKernelGGL(k_pathlin, dim3(512), dim3(512), 0, stream, pe, Whz, bhz, zt);
  hipLaunchKernelGGL(k_trop_node, dim3(768), dim3(512), 0, stream,
                     zt, zt2, node, eidx, Wzz, Wnm, bnm, a1, a3, out0);
  hipLaunchKernelGGL(k_upath, dim3(512), dim3(512), 0, stream,
                     zt2, Wzz, bzz, a1, a3, pe, out1);
}

// Round 15
// 27.261 us; speedup vs baseline: 1.5286x; 1.0140x over previous
//
#include <hip/hip_runtime.h>

// Problem constants (b=4, n=64, d=64, E=4096)
// zt  layout: [b][d][i][k] -> ((b*64+d)*64+i)*64+k   (4 MB)
// zt2: tropical output, same layout (4 MB)
// a1[r][e], a3[r][e] : r = b*64+i (node row), 64 KB each
//
// R15 = R9 (proven 27.3) with all LDS staging converted to async
// global_load_lds width=16 (no VGPR round-trip). Stage patterns are
// byte-linear in t, satisfying the wave-uniform-base + lane*16B rule.

__device__ __forceinline__ void gl_lds16(const float* g, float* lds_wave_base) {
  __builtin_amdgcn_global_load_lds(
      (const __attribute__((address_space(1))) void*)g,
      (__attribute__((address_space(3))) void*)lds_wave_base, 16, 0, 0);
}

// K1: z = pe@Whz + bhz (transposed store) + node MLP + nodeproj. grid = 256 (bi)
__global__ __launch_bounds__(1024) void k_pathlin_node(
    const float* __restrict__ ne, const float* __restrict__ pe,
    const int* __restrict__ eidx,
    const float* __restrict__ Whz, const float* __restrict__ bhz,
    const float* __restrict__ Wzz,
    const float* __restrict__ Wnm, const float* __restrict__ bnm,
    float* __restrict__ zt, float* __restrict__ a1, float* __restrict__ a3,
    float* __restrict__ out0) {
  int bi = blockIdx.x;                    // b*64 + i == node row
  int b = bi >> 6, i = bi & 63;
  int t = threadIdx.x, lane = t & 63, w = t >> 6;   // 16 waves
  __shared__ float sP[4096];              // pe tile [k][c], 16KB
  __shared__ float sW[4096];              // Whz [c][d], 16KB
  __shared__ float part[16][64];
  __shared__ float nl[64], al[64];
  // async stage: wave w covers bytes [w*1024, w*1024+1024) of each tile
  gl_lds16(pe + (size_t)bi * 4096 + t * 4, &sP[w * 256]);
  gl_lds16(Whz + t * 4, &sW[w * 256]);
  float bv = bhz[lane];
  if (w == 0) nl[lane] = ne[bi * 64 + lane];
  __syncthreads();
  // compute: lane = d, wave w owns k in [w*4, w*4+4)
  float acc[4] = {bv, bv, bv, bv};
  int k0 = w * 4;
#pragma unroll
  for (int c = 0; c < 64; c += 4) {
    float w0 = sW[(c + 0) * 64 + lane], w1 = sW[(c + 1) * 64 + lane];
    float w2 = sW[(c + 2) * 64 + lane], w3 = sW[(c + 3) * 64 + lane];
#pragma unroll
    for (int kk = 0; kk < 4; ++kk) {
      const float4 p = *(const float4*)&sP[(k0 + kk) * 64 + c];  // broadcast b128
      acc[kk] += p.x * w0 + p.y * w1 + p.z * w2 + p.w * w3;
    }
  }
  // transposed store: d = lane, 4 consecutive k -> one float4
  float* dst = zt + (size_t)b * 262144 + (size_t)lane * 4096 + (size_t)i * 64 + k0;
  *(float4*)dst = make_float4(acc[0], acc[1], acc[2], acc[3]);
  __syncthreads();                        // pe tile dead; alias as elist
  // ---- node MLP row bi: wave w scans edges [w*256, (w+1)*256) ----
  int* elist = (int*)sP;                  // 4096 ints = 16KB
  const int* srcv = eidx;
  const int* dstv = eidx + 4096;
  int cntw = 0;
  unsigned long long ltmask = (lane == 63) ? 0x7fffffffffffffffull
                                           : ((1ull << lane) - 1ull);
#pragma unroll
  for (int q = 0; q < 4; ++q) {
    int e2 = w * 256 + q * 64 + lane;
    bool match = (dstv[e2] == bi);
    unsigned long long mask = __ballot(match);
    if (match) {
      int pos = cntw + __popcll(mask & ltmask);
      elist[w * 256 + pos] = srcv[e2];
    }
    cntw += __popcll(mask);
  }
  float accA = 0.f;
  for (int m = 0; m < cntw; ++m) accA += ne[elist[w * 256 + m] * 64 + lane];
  part[w][lane] = accA;
  __syncthreads();
  if (w == 0) {
    float s = 0.f;
#pragma unroll
    for (int p2 = 0; p2 < 16; ++p2) s += part[p2][lane];
    al[lane] = s;
  } else if (w == 2) {                    // nodeproj a1
    const float* nr = ne + bi * 64;
    float s1 = 0.f;
    for (int d2 = 0; d2 < 64; ++d2) s1 += nr[d2] * Wzz[d2 * 64 + lane];
    a1[bi * 64 + lane] = s1;
  } else if (w == 3) {                    // nodeproj a3
    const float* nr = ne + bi * 64;
    float s3 = 0.f;
    for (int d2 = 0; d2 < 64; ++d2) s3 += nr[d2] * Wzz[(128 + d2) * 64 + lane];
    a3[bi * 64 + lane] = s3;
  }
  __syncthreads();
  // u_node partials: wave w handles d2 in [w*4, w*4+4)
  {
    float s = 0.f;
#pragma unroll
    for (int dd = 0; dd < 4; ++dd) {
      int d2 = w * 4 + dd;
      s += nl[d2] * Wnm[d2 * 64 + lane] + al[d2] * Wnm[(64 + d2) * 64 + lane];
    }
    part[w][lane] = s;
  }
  __syncthreads();
  if (w == 0) {
    float v = bnm[lane];
#pragma unroll
    for (int p2 = 0; p2 < 16; ++p2) v += part[p2][lane];
    v = fmaxf(v, 0.f);
    out0[bi * 64 + lane] = v + nl[lane];
  }
}

// K2: tropical max-plus per (b,d) slice. grid = 256 (slice)
__global__ __launch_bounds__(1024) void k_tropical(
    const float* __restrict__ zt, float* __restrict__ zt2) {
  int slice = blockIdx.x;                 // b*64 + d
  int t = threadIdx.x, lane = t & 63, w = t >> 6;
  __shared__ float A[4096];               // full 64x64 slice
  const float* Ag = zt + (size_t)slice * 4096;
  gl_lds16(Ag + t * 4, &A[w * 256]);      // async stage, linear
  __syncthreads();
  int i0 = w * 4;                         // wave w owns rows [w*4, w*4+4)
  float acc[4];
#pragma unroll
  for (int ii = 0; ii < 4; ++ii) acc[ii] = A[(i0 + ii) * 64 + lane];  // max(zc,z)
#pragma unroll
  for (int k = 0; k < 64; k += 4) {
    float c0 = A[(k + 0) * 64 + lane], c1 = A[(k + 1) * 64 + lane];
    float c2 = A[(k + 2) * 64 + lane], c3 = A[(k + 3) * 64 + lane];
#pragma unroll
    for (int ii = 0; ii < 4; ++ii) {
      const float4 a = *(const float4*)&A[(i0 + ii) * 64 + k];   // broadcast b128
      float m0 = fmaxf(a.x + c0, a.y + c1);
      float m1 = fmaxf(a.z + c2, a.w + c3);
      acc[ii] = fmaxf(acc[ii], fmaxf(m0, m1));
    }
  }
  float* Og = zt2 + (size_t)slice * 4096 + (size_t)i0 * 64;
#pragma unroll
  for (int ii = 0; ii < 4; ++ii) Og[ii * 64 + lane] = acc[ii];
}

// K3: u_path = relu(a1 + z2@W2 + a3 + bzz) + pe. grid = 256 (bi)
__global__ __launch_bounds__(1024) void k_upath(
    const float* __restrict__ zt2, const float* __restrict__ Wzz,
    const float* __restrict__ bzz, const float* __restrict__ a1,
    const float* __restrict__ a3, const float* __restrict__ pe,
    float* __restrict__ out1) {
  int bi = blockIdx.x;
  int b = bi >> 6, i = bi & 63;
  int t = threadIdx.x, lane = t & 63, w = t >> 6;
  __shared__ float sZ[4096];              // [d][j] 16KB
  __shared__ float sW2[4096];             // W_zz rows 64..127: [d][e] 16KB
  {
    // gather z2[b][d2][i][jo..jo+3]; dest byte offset = 16*t (linear)
    int d2 = t >> 4, jo = (t & 15) * 4;
    const float* src = zt2 + (size_t)b * 262144 + (size_t)d2 * 4096
                     + (size_t)i * 64 + jo;
    gl_lds16(src, &sZ[w * 256]);
  }
  gl_lds16(Wzz + 4096 + t * 4, &sW2[w * 256]);
  float base = a1[bi * 64 + lane] + bzz[lane];
  __syncthreads();
  int j0 = w * 4;                         // wave w owns 4 consecutive j
  float acc[4] = {base, base, base, base};
#pragma unroll
  for (int d = 0; d < 64; ++d) {
    const float4 z4 = *(const float4*)&sZ[d * 64 + j0];   // broadcast b128
    float wv = sW2[d * 64 + lane];                         // b32, conflict-free
    acc[0] += z4.x * wv;
    acc[1] += z4.y * wv;
    acc[2] += z4.z * wv;
    acc[3] += z4.w * wv;
  }
  const float* a3b = a3 + (size_t)b * 4096;
  size_t ob = (size_t)bi * 4096 + (size_t)j0 * 64;
#pragma unroll
  for (int jj = 0; jj < 4; ++jj) {
    float v = acc[jj] + a3b[(j0 + jj) * 64 + lane];
    v = fmaxf(v, 0.f);
    out1[ob + jj * 64 + lane] = v + pe[ob + jj * 64 + lane];
  }
}

extern "C" void kernel_launch(void* const* d_in, const int* in_sizes, int n_in,
                              void* d_out, int out_size, void* d_ws, size_t ws_size,
                              hipStream_t stream) {
  const float* node = (const float*)d_in[0];
  const float* pe   = (const float*)d_in[1];
  const int*   eidx = (const int*)d_in[2];
  const float* Whz  = (const float*)d_in[3];
  const float* bhz  = (const float*)d_in[4];
  const float* Wzz  = (const float*)d_in[5];
  const float* bzz  = (const float*)d_in[6];
  const float* Wnm  = (const float*)d_in[7];
  const float* bnm  = (const float*)d_in[8];
  float* out0 = (float*)d_out;
  float* out1 = out0 + 16384;
  float* zt  = (float*)d_ws;                // 4 MB
  float* zt2 = zt + 1048576;                // 4 MB
  float* a1  = zt2 + 1048576;               // 64 KB
  float* a3  = a1 + 16384;                  // 64 KB

  hipLaunchKernelGGL(k_pathlin_node, dim3(256), dim3(1024), 0, stream,
                     node, pe, eidx, Whz, bhz, Wzz, Wnm, bnm, zt, a1, a3, out0);
  hipLaunchKernelGGL(k_tropical, dim3(256), dim3(1024), 0, stream, zt, zt2);
  hipLaunchKernelGGL(k_upath, dim3(256), dim3(1024), 0, stream,
                     zt2, Wzz, bzz, a1, a3, pe, out1);
}